// Round 6
// baseline (332.732 us; speedup 1.0000x reference)
//
#include <hip/hip_runtime.h>

#define N_NODES 100000
#define N_EDGES 1600000
#define NQUAD (N_EDGES / 4)            // 400000
#define NEG_SLOPE 0.2f
#define NBKT 256
#define BDIV 391                       // ceil(N_NODES/NBKT); 255*391 = 99705
#define CAP 7168                       // per-bucket staging cap (mean 6250, +11 sigma)
#define CHUNK 16                       // LDS flush chunk (128B)
#define P1_BLOCKS 128
#define P1_QPB (NQUAD / P1_BLOCKS)     // 3125 quads per block
#define P1_ROUNDS ((P1_QPB + 255) / 256)  // 13

// clang ext-vector types for __builtin_nontemporal_load
typedef int   vint4   __attribute__((ext_vector_type(4)));
typedef int   vint2   __attribute__((ext_vector_type(2)));
typedef float vfloat4 __attribute__((ext_vector_type(4)));

__device__ __forceinline__ float leaky(float v) { return v >= 0.f ? v : NEG_SLOPE * v; }

// ---------- P1: LDS-staged bucketing by dst/BDIV ----------
// Payload: {src | (dst_local<<17), w}. Full 128B chunks flushed contiguously
// by one thread -> line-dense writes, no RMW, XCD-placement-independent.
__global__ void __launch_bounds__(256) k_bucket(const int* __restrict__ ei,
                                                const float* __restrict__ w,
                                                int* __restrict__ gcur,
                                                int2* __restrict__ staging) {
    __shared__ int2 buf[CHUNK][NBKT];   // [k][b]: flush reads spread banks
    __shared__ int fill[NBKT];
    int tid = threadIdx.x;
    fill[tid] = 0;
    __syncthreads();
    const vint4* src4 = (const vint4*)ei;
    const vint4* dst4 = (const vint4*)(ei + N_EDGES);
    const vfloat4* w4 = (const vfloat4*)w;
    int q0 = blockIdx.x * P1_QPB;
    for (int r = 0; r < P1_ROUNDS; ++r) {
        int q = r * 256 + tid;
        if (q < P1_QPB) {
            int qi = q0 + q;
            vint4 s = __builtin_nontemporal_load(&src4[qi]);
            vint4 d = __builtin_nontemporal_load(&dst4[qi]);
            vfloat4 ww = __builtin_nontemporal_load(&w4[qi]);
#pragma unroll
            for (int j = 0; j < 4; ++j) {
                int dd = (j == 0) ? d.x : (j == 1) ? d.y : (j == 2) ? d.z : d.w;
                int ss = (j == 0) ? s.x : (j == 1) ? s.y : (j == 2) ? s.z : s.w;
                float wv = (j == 0) ? ww.x : (j == 1) ? ww.y : (j == 2) ? ww.z : ww.w;
                int b = dd / BDIV;
                int pk = ss | ((dd - b * BDIV) << 17);
                int slot = atomicAdd(&fill[b], 1);
                if (slot < CHUNK) {
                    buf[slot][b] = make_int2(pk, __float_as_int(wv));
                } else {  // overflow fallback (statistically ~never)
                    int p = atomicAdd(&gcur[b], 1);
                    staging[b * CAP + p] = make_int2(pk, __float_as_int(wv));
                }
            }
        }
        __syncthreads();
        int f = fill[tid];
        if (f >= CHUNK) {
            int base = atomicAdd(&gcur[tid], CHUNK);
            int2* dst = &staging[tid * CAP + base];
            if ((base & 1) == 0) {  // 16B-aligned: vector copy
#pragma unroll
                for (int k = 0; k < CHUNK; k += 2) {
                    int2 a = buf[k][tid], bb2 = buf[k + 1][tid];
                    vint4 v = {a.x, a.y, bb2.x, bb2.y};
                    *(vint4*)(&dst[k]) = v;
                }
            } else {
#pragma unroll
                for (int k = 0; k < CHUNK; ++k) dst[k] = buf[k][tid];
            }
            fill[tid] = 0;
        }
        __syncthreads();
    }
    // tail flush (f < CHUNK)
    int f = fill[tid];
    if (f > 0) {
        int base = atomicAdd(&gcur[tid], f);
        for (int k = 0; k < f; ++k) staging[tid * CAP + base + k] = buf[k][tid];
    }
}

// ---------- P2: bucket-total prefix (1 block) + attention dot-constants ----------
__global__ void k_bscan(const int* __restrict__ gcur, int* __restrict__ bbase,
                        const float* __restrict__ W1, const float* __restrict__ attS1,
                        const float* __restrict__ attD1, const float* __restrict__ We1,
                        const float* __restrict__ attE1, float* __restrict__ consts) {
    __shared__ int sm[NBKT];
    int tid = threadIdx.x;
    if (tid < 8) {
        int r = tid >> 2, h = tid & 3;
        float s = 0.f;
        for (int c = 0; c < 32; ++c) s += W1[r * 128 + h * 32 + c] * attS1[h * 32 + c];
        consts[tid] = s;
    } else if (tid < 16) {
        int u = tid - 8, r = u >> 2, h = u & 3;
        float s = 0.f;
        for (int c = 0; c < 32; ++c) s += W1[r * 128 + h * 32 + c] * attD1[h * 32 + c];
        consts[tid] = s;
    } else if (tid < 20) {
        int h = tid - 16;
        float s = 0.f;
        for (int c = 0; c < 32; ++c) s += We1[h * 32 + c] * attE1[h * 32 + c];
        consts[tid] = s;
    }
    int v = gcur[tid];
    sm[tid] = v;
    __syncthreads();
    for (int off = 1; off < NBKT; off <<= 1) {
        int t = (tid >= off) ? sm[tid - off] : 0;
        __syncthreads();
        sm[tid] += t;
        __syncthreads();
    }
    bbase[tid] = sm[tid] - v;  // exclusive
}

// ---------- P3: per-bucket build: local hist+scan -> deg/cursor, place CSR,
//             fused nodeRec/aD1. One block per bucket: writes stay in one L2.
__global__ void __launch_bounds__(256) k_build(
        const int* __restrict__ gcur, const int* __restrict__ bbase,
        const int2* __restrict__ staging, const float* __restrict__ x,
        const float* __restrict__ consts, int* __restrict__ deg,
        int* __restrict__ cursor, int2* __restrict__ csr,
        float* __restrict__ nodeRec, float* __restrict__ aD1) {
    __shared__ int hist[512];
    __shared__ int lcur[BDIV];
    int b = blockIdx.x, tid = threadIdx.x;
    int cnt = gcur[b];
    int base = bbase[b];
    const int2* st = &staging[b * CAP];
    hist[tid] = 0;
    hist[tid + 256] = 0;
    __syncthreads();
    for (int i = tid; i < cnt; i += 256) atomicAdd(&hist[st[i].x >> 17], 1);
    __syncthreads();
    int h0 = hist[tid], h1 = hist[tid + 256];
    for (int off = 1; off < 512; off <<= 1) {  // inclusive Hillis-Steele over 512
        int a0 = (tid >= off) ? hist[tid - off] : 0;
        int a1 = (tid + 256 >= off) ? hist[tid + 256 - off] : 0;
        __syncthreads();
        hist[tid] += a0;
        hist[tid + 256] += a1;
        __syncthreads();
    }
    int n0 = b * BDIV;
    int nnode = min(BDIV, N_NODES - n0);
    if (tid < nnode)       { deg[n0 + tid] = h0;         cursor[n0 + tid] = base + hist[tid]; }
    if (tid + 256 < nnode) { deg[n0 + tid + 256] = h1;   cursor[n0 + tid + 256] = base + hist[tid + 256]; }
    if (tid < BDIV)        lcur[tid] = hist[tid] - h0;
    if (tid + 256 < BDIV)  lcur[tid + 256] = hist[tid + 256] - h1;
    __syncthreads();
    for (int i = tid; i < cnt; i += 256) {  // placement (L2-hot second read)
        int2 e = st[i];
        int dl = e.x >> 17;
        int pos = atomicAdd(&lcur[dl], 1);
        csr[base + pos] = make_int2(e.x & 0x1FFFF, e.y);
    }
    // fused per-node records for this bucket's node range
    for (int j = tid; j < nnode; j += 256) {
        int n = n0 + j;
        float x0 = x[2 * n], x1 = x[2 * n + 1];
#pragma unroll
        for (int h = 0; h < 4; ++h) {
            nodeRec[n * 8 + h] = x0 * consts[h] + x1 * consts[4 + h];
            aD1[n * 4 + h]     = x0 * consts[8 + h] + x1 * consts[12 + h];
        }
        nodeRec[n * 8 + 4] = x0;
        nodeRec[n * 8 + 5] = x1;
        nodeRec[n * 8 + 6] = 0.f;
        nodeRec[n * 8 + 7] = 0.f;
    }
}

// ---------- K5: layer-1 gather, 8 lanes/node + fused node MLP -> h2 ----------
__global__ void k_gather1(const int* __restrict__ deg, const int* __restrict__ cursor,
                          const int2* __restrict__ csr, const float* __restrict__ nodeRec,
                          const float* __restrict__ aD1, const float* __restrict__ consts,
                          const float* __restrict__ W1, const float* __restrict__ b1,
                          const float* __restrict__ W2, float* __restrict__ h2) {
    __shared__ float w10[132], w11[132], b1s[132], w2s[132];  // stride-33 pad
    for (int j = threadIdx.x; j < 128; j += blockDim.x) {
        int jj = (j >> 5) * 33 + (j & 31);
        w10[jj] = W1[j];
        w11[jj] = W1[128 + j];
        b1s[jj] = b1[j];
        w2s[jj] = W2[j];
    }
    __syncthreads();
    int t = blockIdx.x * blockDim.x + threadIdx.x;
    int n = t >> 3, l = t & 7;
    if (n >= N_NODES) return;
    float cE[4] = {consts[16], consts[17], consts[18], consts[19]};
    int end = cursor[n];
    int d = deg[n];
    int start = end - d;
    float4 ad = *(const float4*)(aD1 + n * 4);
    float adv[4] = {ad.x, ad.y, ad.z, ad.w};
    float s[4] = {0, 0, 0, 0}, X0[4] = {0, 0, 0, 0}, X1[4] = {0, 0, 0, 0};
    float wsum = 0.f;
    const vint2* csr2 = (const vint2*)csr;
    for (int k = start + l; k < end; k += 8) {
        vint2 rec = __builtin_nontemporal_load(&csr2[k]);
        int src = rec.x;
        float wt = __int_as_float(rec.y);
        float4 as = *(const float4*)(nodeRec + src * 8);
        float2 xs = *(const float2*)(nodeRec + src * 8 + 4);
        float asv[4] = {as.x, as.y, as.z, as.w};
        wsum += wt;
#pragma unroll
        for (int h = 0; h < 4; ++h) {
            float p = __expf(leaky(asv[h] + adv[h] + wt * cE[h]));
            s[h] += p;
            X0[h] += p * xs.x;
            X1[h] += p * xs.y;
        }
    }
#pragma unroll
    for (int off = 1; off < 8; off <<= 1) {
        wsum += __shfl_xor(wsum, off);
#pragma unroll
        for (int h = 0; h < 4; ++h) {
            s[h]  += __shfl_xor(s[h], off);
            X0[h] += __shfl_xor(X0[h], off);
            X1[h] += __shfl_xor(X1[h], off);
        }
    }
    float la = wsum / fmaxf((float)d, 1.f);  // self loop: mean incident weight
    float4 aso = *(const float4*)(nodeRec + n * 8);
    float2 xo = *(const float2*)(nodeRec + n * 8 + 4);
    float asov[4] = {aso.x, aso.y, aso.z, aso.w};
#pragma unroll
    for (int h = 0; h < 4; ++h) {
        float p = __expf(leaky(asov[h] + adv[h] + la * cE[h]));
        s[h] += p;
        X0[h] += p * xo.x;
        X1[h] += p * xo.y;
    }
    int hh = l & 3;  // lane -> head l&3, channel-half l>>2
    float sh  = (hh == 0) ? s[0]  : (hh == 1) ? s[1]  : (hh == 2) ? s[2]  : s[3];
    float X0h = (hh == 0) ? X0[0] : (hh == 1) ? X0[1] : (hh == 2) ? X0[2] : X0[3];
    float X1h = (hh == 0) ? X1[0] : (hh == 1) ? X1[1] : (hh == 2) ? X1[2] : X1[3];
    float inv = 1.f / (sh + 1e-16f);
    X0h *= inv;
    X1h *= inv;
    float acc = 0.f;
    int basej = hh * 33 + (l >> 2) * 16;
    for (int c = 0; c < 16; ++c) {
        float v = X0h * w10[basej + c] + X1h * w11[basej + c] + b1s[basej + c];
        float el = v > 0.f ? v : __expf(v) - 1.f;  // elu
        acc += el * w2s[basej + c];
    }
    acc += __shfl_xor(acc, 1);
    acc += __shfl_xor(acc, 2);
    acc += __shfl_xor(acc, 4);
    if (l == 0) h2[n] = acc;
}

// ---------- K6: layer-2 gather, 8 lanes/node -> out ----------
__global__ void k_gather2(const int* __restrict__ deg, const int* __restrict__ cursor,
                          const int2* __restrict__ csr, const float* __restrict__ h2,
                          const float* __restrict__ attS2, const float* __restrict__ attD2,
                          const float* __restrict__ We2, const float* __restrict__ attE2,
                          const float* __restrict__ b2, float* __restrict__ out) {
    int t = blockIdx.x * blockDim.x + threadIdx.x;
    int n = t >> 3, l = t & 7;
    if (n >= N_NODES) return;
    float aS = attS2[0], aD = attD2[0], cE = We2[0] * attE2[0], bb = b2[0];
    int end = cursor[n];
    int d = deg[n];
    int start = end - d;
    float hn = h2[n];
    float hnaD = hn * aD;
    float s = 0.f, acc = 0.f, wsum = 0.f;
    const vint2* csr2 = (const vint2*)csr;
    for (int k = start + l; k < end; k += 8) {
        vint2 rec = __builtin_nontemporal_load(&csr2[k]);
        float hs = h2[rec.x];
        float wt = __int_as_float(rec.y);
        wsum += wt;
        float p = __expf(leaky(hs * aS + hnaD + wt * cE));
        s += p;
        acc += p * hs;
    }
#pragma unroll
    for (int off = 1; off < 8; off <<= 1) {
        wsum += __shfl_xor(wsum, off);
        s    += __shfl_xor(s, off);
        acc  += __shfl_xor(acc, off);
    }
    float la = wsum / fmaxf((float)d, 1.f);
    float p = __expf(leaky(hn * aS + hnaD + la * cE));
    s += p;
    acc += p * hn;
    if (l == 0) out[n] = acc / (s + 1e-16f) + bb;
}

extern "C" void kernel_launch(void* const* d_in, const int* in_sizes, int n_in,
                              void* d_out, int out_size, void* d_ws, size_t ws_size,
                              hipStream_t stream) {
    const float* x     = (const float*)d_in[0];
    const int*   ei    = (const int*)d_in[1];
    const float* w     = (const float*)d_in[2];
    const float* W1    = (const float*)d_in[3];
    const float* attS1 = (const float*)d_in[4];
    const float* attD1 = (const float*)d_in[5];
    const float* We1   = (const float*)d_in[6];
    const float* attE1 = (const float*)d_in[7];
    const float* b1    = (const float*)d_in[8];
    const float* W2    = (const float*)d_in[9];
    const float* attS2 = (const float*)d_in[10];
    const float* attD2 = (const float*)d_in[11];
    const float* We2   = (const float*)d_in[12];
    const float* attE2 = (const float*)d_in[13];
    const float* b2    = (const float*)d_in[14];
    float* out = (float*)d_out;

    const int N = N_NODES;

    // workspace layout
    int*   gcur    = (int*)d_ws;                  // 256
    int*   bbase   = gcur + 256;                  // 256
    float* consts  = (float*)(bbase + 256);       // 32
    int*   deg     = (int*)(consts + 32);         // N
    int*   cursor  = deg + N;                     // N
    int2*  csr     = (int2*)(cursor + N);         // E      (8B-aligned)
    int2*  staging = csr + N_EDGES;               // NBKT*CAP
    float* nodeRec = (float*)(staging + NBKT * CAP);  // 8N  (16B-aligned)
    float* aD1     = nodeRec + 8 * (size_t)N;     // 4N
    float* h2      = aD1 + 4 * (size_t)N;         // N

    (void)hipMemsetAsync(gcur, 0, 256 * sizeof(int), stream);

    k_bucket<<<P1_BLOCKS, 256, 0, stream>>>(ei, w, gcur, staging);
    k_bscan<<<1, 256, 0, stream>>>(gcur, bbase, W1, attS1, attD1, We1, attE1, consts);
    k_build<<<NBKT, 256, 0, stream>>>(gcur, bbase, staging, x, consts, deg, cursor, csr,
                                      nodeRec, aD1);
    k_gather1<<<(8 * N + 255) / 256, 256, 0, stream>>>(deg, cursor, csr, nodeRec, aD1,
                                                       consts, W1, b1, W2, h2);
    k_gather2<<<(8 * N + 255) / 256, 256, 0, stream>>>(deg, cursor, csr, h2, attS2, attD2,
                                                       We2, attE2, b2, out);
}